// Round 7
// baseline (87.208 us; speedup 1.0000x reference)
//
#include <hip/hip_runtime.h>
#include <math.h>

#define TT 24
#define SS 200
#define CIN 8
#define CW 32
#define NSC 6400      // SS*CW
#define NTOT 153600   // TT*SS*CW

// ws layout (float offsets)
#define DTOFF   0       // dinv_t [24]
#define DSOFF   32      // dinv_s [200]
#define DS2OFF  288     // dinv_s^2 [200]
#define ATOFF   512     // At-hat [576]
#define AT2OFF  1088    // At-hat^2 [576]
#define AS2OFF  2048    // As-hat^2 [40000]
#define XOFF    42048   // X (U0) [153600]
#define M0AOFF  195648
#define M0BOFF  349248
#define M1OFF   502848
#define M2OFF   656448
#define M3OFF   810048  // end 963648 floats ~ 3.86 MB

// wave-parallel dinv_s: 4 waves x 50 rows, coalesced row sums
__device__ __forceinline__ void dinv_rows(const float* __restrict__ As,
                                          float* sd, float* sd2) {
    const int wv = threadIdx.x >> 6, ln = threadIdx.x & 63;
    for (int r = wv*50; r < wv*50 + 50; ++r) {
        float v = As[r*SS + ln] + As[r*SS + 64 + ln] + As[r*SS + 128 + ln];
        if (ln < SS - 192) v += As[r*SS + 192 + ln];
        #pragma unroll
        for (int off = 32; off; off >>= 1) v += __shfl_xor(v, off, 64);
        if (ln == 0) { const float d = 1.f / sqrtf(v); sd[r] = d; sd2[r] = d*d; }
    }
}

// ---------------- kprep: blocks 0..156 As-hat^2; block 157 dinv/At/At^2 ----
__global__ __launch_bounds__(256)
void kprep(const float* __restrict__ At, const float* __restrict__ As,
           float* __restrict__ ws) {
    __shared__ float sd[SS], sd2[SS];
    __shared__ float sAt[TT*TT];
    __shared__ float sdt[TT];
    const int tid = threadIdx.x;
    dinv_rows(As, sd, sd2);
    if (blockIdx.x == 157) {
        if (tid < TT) {
            float sum = 0.f;
            #pragma unroll
            for (int j = 0; j < TT; ++j) sum += At[tid*TT + j];
            const float d = 1.f / sqrtf(sum);
            sdt[tid] = d;
            ws[DTOFF + tid] = d;
        }
        __syncthreads();
        if (tid < SS) { ws[DSOFF + tid] = sd[tid]; ws[DS2OFF + tid] = sd2[tid]; }
        for (int i = tid; i < TT*TT; i += 256) {
            const int t = i / TT, tp = i % TT;
            const float v = At[i] * sdt[t] * sdt[tp] * 0.5f;
            sAt[i] = v;
            ws[ATOFF + i] = v;
        }
        __syncthreads();
        for (int i = tid; i < TT*TT; i += 256) {
            const int t = i / TT, tp = i % TT;
            float acc = 0.f;
            #pragma unroll
            for (int k = 0; k < TT; ++k) acc += sAt[t*TT + k] * sAt[k*TT + tp];
            ws[AT2OFF + i] = acc;
        }
        return;
    }
    __syncthreads();
    const int e = blockIdx.x*256 + tid;
    if (e >= SS*SS) return;
    const int i = e / SS, j = e % SS;
    const float4* ri = (const float4*)(As + i*SS);
    const float4* rj = (const float4*)(As + j*SS);
    float acc = 0.f;
    #pragma unroll 5
    for (int q = 0; q < SS/4; ++q) {
        const float4 a = ri[q], b = rj[q];
        acc += a.x*b.x*sd2[4*q]   + a.y*b.y*sd2[4*q+1]
             + a.z*b.z*sd2[4*q+2] + a.w*b.w*sd2[4*q+3];
    }
    ws[AS2OFF + e] = 0.25f * sd[i] * sd[j] * acc;
}

// ---------------- kA: spatial U1,U2 + fold into M arrays -------------------
// FIRST: computes X = xin@Wf+bf for its whole t-slab in LDS (no X dispatch).
template<bool FIRST>
__global__ __launch_bounds__(256, 3)
void kA(const float* __restrict__ xin, const float* __restrict__ As,
        const float* __restrict__ Wf, const float* __restrict__ bf,
        const float* __restrict__ svec, float* __restrict__ ws, int b)
{
    __shared__ float2 sXI[NSC];     // (X, d_k*X) interleaved: ds_read_b64, 2-way ok
    __shared__ float sd[SS];
    __shared__ float sWf[CIN*CW];
    const int tid = threadIdx.x;
    const int t = blockIdx.x / 25, sg = blockIdx.x % 25;
    const int sc = sg*256 + tid;
    const int gid = t*NSC + sc;
    const int c = tid & 31;
    const int s = sg*8 + (tid >> 5);

    if (tid < SS) sd[tid] = ws[DSOFF + tid];
    if (FIRST) sWf[tid] = Wf[tid];      // CIN*CW == 256 exactly
    __syncthreads();

    if (FIRST) {
        const float bfc = bf[c];
        #pragma unroll
        for (int k = 0; k < 25; ++k) {
            const int e = k*256 + tid;          // e&31 == c
            const int sp = e >> 5;
            const float* xr = xin + (t*SS + sp)*CIN;
            float acc = bfc;
            #pragma unroll
            for (int i = 0; i < CIN; ++i) acc += xr[i] * sWf[i*CW + c];
            sXI[e] = make_float2(acc, acc * sd[sp]);
        }
    } else {
        const float* Xg = ws + XOFF + t*NSC;
        #pragma unroll
        for (int k = 0; k < 25; ++k) {
            const int e = k*256 + tid;
            const float v = Xg[e];
            sXI[e] = make_float2(v, v * sd[e >> 5]);
        }
    }
    __syncthreads();

    const float s0 = svec[b*4+0], s1 = svec[b*4+1];
    const float s2 = svec[b*4+2], s3 = svec[b*4+3];
    const float b00 = s0*s0, b01 = 2.f*s0*s1, b02 = s1*s1;
    const float b10 = 2.f*s0*s2, b11 = 2.f*(s0*s3 + s1*s2), b12 = 2.f*s1*s3;
    const float b20 = s2*s2, b21 = 2.f*s2*s3, b22 = s3*s3;

    const float4* ra = (const float4*)(As + s*SS);
    const float4* rq = (const float4*)(ws + AS2OFF + s*SS);
    float u1 = 0.f, u2 = 0.f;
    #pragma unroll 5
    for (int q = 0; q < SS/4; ++q) {
        const float4 a = ra[q], w2 = rq[q];
        const float2 x0 = sXI[(4*q+0)*CW + c];
        const float2 x1 = sXI[(4*q+1)*CW + c];
        const float2 x2 = sXI[(4*q+2)*CW + c];
        const float2 x3 = sXI[(4*q+3)*CW + c];
        u1 += a.x*x0.y + a.y*x1.y + a.z*x2.y + a.w*x3.y;
        u2 += w2.x*x0.x + w2.y*x1.x + w2.z*x2.x + w2.w*x3.x;
    }
    u1 *= 0.5f * sd[s];
    const float x0v = sXI[sc].x;

    if (FIRST) ws[XOFF + gid] = x0v;
    ws[M0AOFF + gid] = s0*x0v + s1*u1;
    ws[M0BOFF + gid] = b00*x0v + b01*u1 + b02*u2;
    ws[M1OFF  + gid] = s2*x0v + s3*u1;
    ws[M2OFF  + gid] = b10*x0v + b11*u1 + b12*u2;
    ws[M3OFF  + gid] = b20*x0v + b21*u1 + b22*u2;
}

// ---------------- kB: temporal dots + epilogue (+ final out for last) -----
__global__ __launch_bounds__(256)
void kB(const float* __restrict__ xin, const float* __restrict__ H,
        const float* __restrict__ mW1, const float* __restrict__ mb1,
        const float* __restrict__ mW2, const float* __restrict__ mb2,
        const float* __restrict__ Wl, const float* __restrict__ bl,
        float* __restrict__ ws, float* __restrict__ out, int b, int last) {
    __shared__ float sAt[2*TT*TT];     // At-hat, At-hat^2
    __shared__ float sH[3*CW*CW];
    __shared__ float sW1[(CW+CIN)*CW];
    __shared__ float sW2[CW*CW];
    __shared__ float sb1[CW], sb2[CW];
    __shared__ float sx[256], sp1[256], sp2[256], sxt[256], sh[256];
    __shared__ float sxin[8*CIN];

    const int tid = threadIdx.x;
    const int gid = blockIdx.x*256 + tid;
    const int t = gid / NSC;           // block-uniform
    const int sc = gid - t*NSC;
    const int r = tid >> 5, c = tid & 31;
    const int node = gid >> 5;

    const float* Hb = H   + b*3*CW*CW;
    const float* W1 = mW1 + b*(CW+CIN)*CW;
    const float* W2 = mW2 + b*CW*CW;

    for (int i = tid; i < 2*TT*TT; i += 256) sAt[i] = ws[ATOFF + i];
    for (int i = tid; i < 3*CW*CW; i += 256) sH[i] = Hb[i];
    for (int i = tid; i < (CW+CIN)*CW; i += 256) sW1[i] = W1[i];
    for (int i = tid; i < CW*CW; i += 256) sW2[i] = W2[i];
    if (tid < CW) { sb1[tid] = mb1[b*CW + tid]; sb2[tid] = mb2[b*CW + tid]; }
    sx[tid] = ws[XOFF + gid];
    if (c < CIN) sxin[r*CIN + c] = xin[node*CIN + c];
    __syncthreads();

    {
        const float* M1 = ws + M1OFF + sc;
        const float* M2 = ws + M2OFF + sc;
        const float* M3 = ws + M3OFF + sc;
        float d1 = 0.f, d2 = 0.f, d3 = 0.f;
        #pragma unroll
        for (int tp = 0; tp < TT; ++tp) {
            const float a1 = sAt[t*TT + tp];
            const float a2 = sAt[TT*TT + t*TT + tp];
            d1 += a1 * M1[tp*NSC];
            d2 += a1 * M2[tp*NSC];
            d3 += a2 * M3[tp*NSC];
        }
        sp1[tid] = ws[M0AOFF + gid] + d1;
        sp2[tid] = ws[M0BOFF + gid] + d2 + d3;
    }
    __syncthreads();
    {
        float acc = 0.f;
        #pragma unroll 8
        for (int cp = 0; cp < CW; ++cp) {
            acc += sx[r*CW + cp]  * sH[cp*CW + c];
            acc += sp1[r*CW + cp] * sH[CW*CW + cp*CW + c];
            acc += sp2[r*CW + cp] * sH[2*CW*CW + cp*CW + c];
        }
        sxt[tid] = tanhf(acc);
    }
    __syncthreads();
    {
        float h = sb1[c];
        #pragma unroll 8
        for (int cp = 0; cp < CW; ++cp) h += sxt[r*CW + cp] * sW1[cp*CW + c];
        #pragma unroll
        for (int i = 0; i < CIN; ++i) h += sxin[r*CIN + i] * sW1[(CW+i)*CW + c];
        sh[tid] = fmaxf(h, 0.f);
    }
    __syncthreads();
    {
        float xn = sb2[c];
        #pragma unroll 8
        for (int cp = 0; cp < CW; ++cp) xn += sh[r*CW + cp] * sW2[cp*CW + c];
        if (!last) {
            ws[XOFF + gid] = xn;
        } else {
            float v = xn * Wl[c];
            #pragma unroll
            for (int off = 16; off; off >>= 1) v += __shfl_xor(v, off, 64);
            if (c == 0) out[node] = v + bl[0];
        }
    }
}

extern "C" void kernel_launch(void* const* d_in, const int* in_sizes, int n_in,
                              void* d_out, int out_size, void* d_ws, size_t ws_size,
                              hipStream_t stream) {
    const float* xin   = (const float*)d_in[0];
    const float* Adj_t = (const float*)d_in[1];
    const float* Adj_s = (const float*)d_in[2];
    const float* H     = (const float*)d_in[3];
    const float* svec  = (const float*)d_in[4];
    const float* Wf    = (const float*)d_in[5];
    const float* bf    = (const float*)d_in[6];
    const float* Wl    = (const float*)d_in[7];
    const float* bl    = (const float*)d_in[8];
    const float* mW1   = (const float*)d_in[9];
    const float* mb1   = (const float*)d_in[10];
    const float* mW2   = (const float*)d_in[11];
    const float* mb2   = (const float*)d_in[12];
    float* out = (float*)d_out;
    float* ws  = (float*)d_ws;

    kprep<<<158, 256, 0, stream>>>(Adj_t, Adj_s, ws);
    kA<true><<<600, 256, 0, stream>>>(xin, Adj_s, Wf, bf, svec, ws, 0);
    kB<<<600, 256, 0, stream>>>(xin, H, mW1, mb1, mW2, mb2, Wl, bl,
                                ws, out, 0, 0);
    kA<false><<<600, 256, 0, stream>>>(xin, Adj_s, Wf, bf, svec, ws, 1);
    kB<<<600, 256, 0, stream>>>(xin, H, mW1, mb1, mW2, mb2, Wl, bl,
                                ws, out, 1, 1);
}

// Round 8
// 67.104 us; speedup vs baseline: 1.2996x; 1.2996x over previous
//
#include <hip/hip_runtime.h>
#include <math.h>

#define TT 24
#define SS 200
#define CIN 8
#define CW 32
#define NSC 6400      // SS*CW
#define NTOT 153600   // TT*SS*CW

// ws layout (float offsets)
#define DTOFF   0       // dinv_t [24]
#define DSOFF   32      // dinv_s [200]
#define DS2OFF  288     // dinv_s^2 [200]
#define ATOFF   512     // At-hat [576]
#define AT2OFF  1088    // At-hat^2 [576]
#define AS2OFF  2048    // As-hat^2 [40000]
#define XOFF    42048   // X (U0) [153600]
#define M0AOFF  195648
#define M0BOFF  349248
#define M1OFF   502848
#define M2OFF   656448
#define M3OFF   810048  // end 963648 floats ~ 3.86 MB

// ---------------- kprep: blocks 0..156 As-hat^2; block 157 dinv/At/At^2 ----
// R7 bug: per-wave serial row-sum loop (50 dependent iterations) made every
// block spend ~40 us. Fix: As is symmetric -> row sums == column sums, so
// thread j accumulates As[i*SS+j] over i: 200 INDEPENDENT coalesced loads,
// fully pipelined (~1 us).
__global__ __launch_bounds__(256)
void kprep(const float* __restrict__ At, const float* __restrict__ As,
           float* __restrict__ ws) {
    __shared__ float sd[SS], sd2[SS];
    __shared__ float sAt[TT*TT];
    __shared__ float sdt[TT];
    const int tid = threadIdx.x;

    if (tid < SS) {
        float sum = 0.f;
        #pragma unroll 8
        for (int i = 0; i < SS; ++i) sum += As[i*SS + tid];
        const float d = 1.f / sqrtf(sum);
        sd[tid] = d;
        sd2[tid] = d * d;
    }
    __syncthreads();

    if (blockIdx.x == 157) {
        if (tid < SS) { ws[DSOFF + tid] = sd[tid]; ws[DS2OFF + tid] = sd2[tid]; }
        if (tid < TT) {
            float sum = 0.f;
            #pragma unroll
            for (int j = 0; j < TT; ++j) sum += At[tid*TT + j];
            const float d = 1.f / sqrtf(sum);
            sdt[tid] = d;
            ws[DTOFF + tid] = d;
        }
        __syncthreads();
        for (int i = tid; i < TT*TT; i += 256) {
            const int t = i / TT, tp = i % TT;
            const float v = At[i] * sdt[t] * sdt[tp] * 0.5f;
            sAt[i] = v;
            ws[ATOFF + i] = v;
        }
        __syncthreads();
        for (int i = tid; i < TT*TT; i += 256) {
            const int t = i / TT, tp = i % TT;
            float acc = 0.f;
            #pragma unroll
            for (int k = 0; k < TT; ++k) acc += sAt[t*TT + k] * sAt[k*TT + tp];
            ws[AT2OFF + i] = acc;
        }
        return;
    }

    const int e = blockIdx.x*256 + tid;
    if (e >= SS*SS) return;
    const int i = e / SS, j = e % SS;
    const float4* ri = (const float4*)(As + i*SS);
    const float4* rj = (const float4*)(As + j*SS);
    float acc = 0.f;
    #pragma unroll 5
    for (int q = 0; q < SS/4; ++q) {
        const float4 a = ri[q], b = rj[q];
        acc += a.x*b.x*sd2[4*q]   + a.y*b.y*sd2[4*q+1]
             + a.z*b.z*sd2[4*q+2] + a.w*b.w*sd2[4*q+3];
    }
    ws[AS2OFF + e] = 0.25f * sd[i] * sd[j] * acc;
}

// ---------------- kA: spatial U1,U2 + fold into M arrays -------------------
// FIRST: computes X = xin@Wf+bf for its whole t-slab in LDS (no X dispatch).
template<bool FIRST>
__global__ __launch_bounds__(256, 3)
void kA(const float* __restrict__ xin, const float* __restrict__ As,
        const float* __restrict__ Wf, const float* __restrict__ bf,
        const float* __restrict__ svec, float* __restrict__ ws, int b)
{
    __shared__ float2 sXI[NSC];     // (X, d_k*X) interleaved: ds_read_b64, 2-way ok
    __shared__ float sd[SS];
    __shared__ float sWf[CIN*CW];
    const int tid = threadIdx.x;
    const int t = blockIdx.x / 25, sg = blockIdx.x % 25;
    const int sc = sg*256 + tid;
    const int gid = t*NSC + sc;
    const int c = tid & 31;
    const int s = sg*8 + (tid >> 5);

    if (tid < SS) sd[tid] = ws[DSOFF + tid];
    if (FIRST) sWf[tid] = Wf[tid];      // CIN*CW == 256 exactly
    __syncthreads();

    if (FIRST) {
        const float bfc = bf[c];
        #pragma unroll
        for (int k = 0; k < 25; ++k) {
            const int e = k*256 + tid;          // e&31 == c
            const int sp = e >> 5;
            const float* xr = xin + (t*SS + sp)*CIN;
            float acc = bfc;
            #pragma unroll
            for (int i = 0; i < CIN; ++i) acc += xr[i] * sWf[i*CW + c];
            sXI[e] = make_float2(acc, acc * sd[sp]);
        }
    } else {
        const float* Xg = ws + XOFF + t*NSC;
        #pragma unroll
        for (int k = 0; k < 25; ++k) {
            const int e = k*256 + tid;
            const float v = Xg[e];
            sXI[e] = make_float2(v, v * sd[e >> 5]);
        }
    }
    __syncthreads();

    const float s0 = svec[b*4+0], s1 = svec[b*4+1];
    const float s2 = svec[b*4+2], s3 = svec[b*4+3];
    const float b00 = s0*s0, b01 = 2.f*s0*s1, b02 = s1*s1;
    const float b10 = 2.f*s0*s2, b11 = 2.f*(s0*s3 + s1*s2), b12 = 2.f*s1*s3;
    const float b20 = s2*s2, b21 = 2.f*s2*s3, b22 = s3*s3;

    const float4* ra = (const float4*)(As + s*SS);
    const float4* rq = (const float4*)(ws + AS2OFF + s*SS);
    float u1 = 0.f, u2 = 0.f;
    #pragma unroll 5
    for (int q = 0; q < SS/4; ++q) {
        const float4 a = ra[q], w2 = rq[q];
        const float2 x0 = sXI[(4*q+0)*CW + c];
        const float2 x1 = sXI[(4*q+1)*CW + c];
        const float2 x2 = sXI[(4*q+2)*CW + c];
        const float2 x3 = sXI[(4*q+3)*CW + c];
        u1 += a.x*x0.y + a.y*x1.y + a.z*x2.y + a.w*x3.y;
        u2 += w2.x*x0.x + w2.y*x1.x + w2.z*x2.x + w2.w*x3.x;
    }
    u1 *= 0.5f * sd[s];
    const float x0v = sXI[sc].x;

    if (FIRST) ws[XOFF + gid] = x0v;
    ws[M0AOFF + gid] = s0*x0v + s1*u1;
    ws[M0BOFF + gid] = b00*x0v + b01*u1 + b02*u2;
    ws[M1OFF  + gid] = s2*x0v + s3*u1;
    ws[M2OFF  + gid] = b10*x0v + b11*u1 + b12*u2;
    ws[M3OFF  + gid] = b20*x0v + b21*u1 + b22*u2;
}

// ---------------- kB: temporal dots + epilogue (+ final out for last) -----
__global__ __launch_bounds__(256)
void kB(const float* __restrict__ xin, const float* __restrict__ H,
        const float* __restrict__ mW1, const float* __restrict__ mb1,
        const float* __restrict__ mW2, const float* __restrict__ mb2,
        const float* __restrict__ Wl, const float* __restrict__ bl,
        float* __restrict__ ws, float* __restrict__ out, int b, int last) {
    __shared__ float sAt[2*TT*TT];     // At-hat, At-hat^2
    __shared__ float sH[3*CW*CW];
    __shared__ float sW1[(CW+CIN)*CW];
    __shared__ float sW2[CW*CW];
    __shared__ float sb1[CW], sb2[CW];
    __shared__ float sx[256], sp1[256], sp2[256], sxt[256], sh[256];
    __shared__ float sxin[8*CIN];

    const int tid = threadIdx.x;
    const int gid = blockIdx.x*256 + tid;
    const int t = gid / NSC;           // block-uniform
    const int sc = gid - t*NSC;
    const int r = tid >> 5, c = tid & 31;
    const int node = gid >> 5;

    const float* Hb = H   + b*3*CW*CW;
    const float* W1 = mW1 + b*(CW+CIN)*CW;
    const float* W2 = mW2 + b*CW*CW;

    for (int i = tid; i < 2*TT*TT; i += 256) sAt[i] = ws[ATOFF + i];
    for (int i = tid; i < 3*CW*CW; i += 256) sH[i] = Hb[i];
    for (int i = tid; i < (CW+CIN)*CW; i += 256) sW1[i] = W1[i];
    for (int i = tid; i < CW*CW; i += 256) sW2[i] = W2[i];
    if (tid < CW) { sb1[tid] = mb1[b*CW + tid]; sb2[tid] = mb2[b*CW + tid]; }
    sx[tid] = ws[XOFF + gid];
    if (c < CIN) sxin[r*CIN + c] = xin[node*CIN + c];
    __syncthreads();

    {
        const float* M1 = ws + M1OFF + sc;
        const float* M2 = ws + M2OFF + sc;
        const float* M3 = ws + M3OFF + sc;
        float d1 = 0.f, d2 = 0.f, d3 = 0.f;
        #pragma unroll
        for (int tp = 0; tp < TT; ++tp) {
            const float a1 = sAt[t*TT + tp];
            const float a2 = sAt[TT*TT + t*TT + tp];
            d1 += a1 * M1[tp*NSC];
            d2 += a1 * M2[tp*NSC];
            d3 += a2 * M3[tp*NSC];
        }
        sp1[tid] = ws[M0AOFF + gid] + d1;
        sp2[tid] = ws[M0BOFF + gid] + d2 + d3;
    }
    __syncthreads();
    {
        float acc = 0.f;
        #pragma unroll 8
        for (int cp = 0; cp < CW; ++cp) {
            acc += sx[r*CW + cp]  * sH[cp*CW + c];
            acc += sp1[r*CW + cp] * sH[CW*CW + cp*CW + c];
            acc += sp2[r*CW + cp] * sH[2*CW*CW + cp*CW + c];
        }
        sxt[tid] = tanhf(acc);
    }
    __syncthreads();
    {
        float h = sb1[c];
        #pragma unroll 8
        for (int cp = 0; cp < CW; ++cp) h += sxt[r*CW + cp] * sW1[cp*CW + c];
        #pragma unroll
        for (int i = 0; i < CIN; ++i) h += sxin[r*CIN + i] * sW1[(CW+i)*CW + c];
        sh[tid] = fmaxf(h, 0.f);
    }
    __syncthreads();
    {
        float xn = sb2[c];
        #pragma unroll 8
        for (int cp = 0; cp < CW; ++cp) xn += sh[r*CW + cp] * sW2[cp*CW + c];
        if (!last) {
            ws[XOFF + gid] = xn;
        } else {
            float v = xn * Wl[c];
            #pragma unroll
            for (int off = 16; off; off >>= 1) v += __shfl_xor(v, off, 64);
            if (c == 0) out[node] = v + bl[0];
        }
    }
}

extern "C" void kernel_launch(void* const* d_in, const int* in_sizes, int n_in,
                              void* d_out, int out_size, void* d_ws, size_t ws_size,
                              hipStream_t stream) {
    const float* xin   = (const float*)d_in[0];
    const float* Adj_t = (const float*)d_in[1];
    const float* Adj_s = (const float*)d_in[2];
    const float* H     = (const float*)d_in[3];
    const float* svec  = (const float*)d_in[4];
    const float* Wf    = (const float*)d_in[5];
    const float* bf    = (const float*)d_in[6];
    const float* Wl    = (const float*)d_in[7];
    const float* bl    = (const float*)d_in[8];
    const float* mW1   = (const float*)d_in[9];
    const float* mb1   = (const float*)d_in[10];
    const float* mW2   = (const float*)d_in[11];
    const float* mb2   = (const float*)d_in[12];
    float* out = (float*)d_out;
    float* ws  = (float*)d_ws;

    kprep<<<158, 256, 0, stream>>>(Adj_t, Adj_s, ws);
    kA<true><<<600, 256, 0, stream>>>(xin, Adj_s, Wf, bf, svec, ws, 0);
    kB<<<600, 256, 0, stream>>>(xin, H, mW1, mb1, mW2, mb2, Wl, bl,
                                ws, out, 0, 0);
    kA<false><<<600, 256, 0, stream>>>(xin, Adj_s, Wf, bf, svec, ws, 1);
    kB<<<600, 256, 0, stream>>>(xin, H, mW1, mb1, mW2, mb2, Wl, bl,
                                ws, out, 1, 1);
}

// Round 9
// 53.504 us; speedup vs baseline: 1.6299x; 1.2542x over previous
//
#include <hip/hip_runtime.h>
#include <math.h>

#define TT 24
#define SS 200
#define CIN 8
#define CW 32
#define NSC 6400      // SS*CW
#define NTOT 153600   // TT*SS*CW

// ws layout (float offsets)
#define DSOFF   0        // dinv_s [200]
#define ATOFF   256      // At-hat [576]
#define AT2OFF  832      // At-hat^2 [576]  (contiguous after ATOFF)
#define XOFF    1408     // X [153600]
#define M0AOFF  155008
#define M0BOFF  308608
#define M1OFF   462208
#define M2OFF   615808
#define M3OFF   769408   // end 923008 floats ~3.69 MB

// ---------------- kSp: spatial passes, one block = (t, 4-channel group) ----
// U1 = As-hat X, U2 = As-hat U1 computed sequentially in-block (no As^2
// precompute, no kprep dispatch). 1024 thr: thread=(q,s); each dot split
// 4-way over sp with LDS partial reduce. As reads are coalesced via symmetry
// (As[sp*SS+s], lane-s consecutive); sXd[sp] reads are uniform-address
// broadcasts (free). FIRST also computes X = xin@Wf+bf; block 192 does
// At-hat/At-hat^2 prep.
template<bool FIRST>
__global__ __launch_bounds__(1024)
void kSp(const float* __restrict__ xin, const float* __restrict__ At,
         const float* __restrict__ As, const float* __restrict__ Wf,
         const float* __restrict__ bf, const float* __restrict__ svec,
         float* __restrict__ ws, int b)
{
    __shared__ float4 sXd[SS];        // d_sp * X[sp, c0..c0+3]
    __shared__ float4 sX[SS];         // X
    __shared__ float4 sU[SS];         // d_s * U1
    __shared__ float4 spart[4][SS];   // partial sums
    __shared__ float  sd[256];
    __shared__ float  sdt[TT];
    __shared__ float  sAt[TT*TT];

    const int tid = threadIdx.x;

    if (FIRST && blockIdx.x == 192) {
        // At prep (1024 threads: single guards are safe, 576 < 1024)
        if (tid < TT) {
            float sum = 0.f;
            #pragma unroll
            for (int i = 0; i < TT; ++i) sum += At[i*TT + tid];
            sdt[tid] = 1.f / sqrtf(sum);
        }
        __syncthreads();
        if (tid < TT*TT) {
            const int i = tid / TT, j = tid % TT;
            const float v = At[tid] * sdt[i] * sdt[j] * 0.5f;
            sAt[tid] = v;
            ws[ATOFF + tid] = v;
        }
        __syncthreads();
        if (tid < TT*TT) {
            const int i = tid / TT, j = tid % TT;
            float acc = 0.f;
            #pragma unroll
            for (int k = 0; k < TT; ++k) acc += sAt[i*TT + k] * sAt[k*TT + j];
            ws[AT2OFF + tid] = acc;
        }
        return;
    }

    const int q = tid >> 8;          // 0..3 (sp quarter)
    const int s = tid & 255;         // spatial row; active if <200
    const bool act = s < SS;
    const int t  = blockIdx.x >> 3;
    const int c0 = (blockIdx.x & 7) * 4;

    // ---- dinv_s ----
    if (FIRST) {
        if (act) {
            float v = 0.f;
            #pragma unroll 5
            for (int i = q*50; i < q*50 + 50; ++i) v += As[i*SS + s];
            spart[q][s].x = v;
        }
        __syncthreads();
        if (q == 0 && act) {
            const float sum = spart[0][s].x + spart[1][s].x
                            + spart[2][s].x + spart[3][s].x;
            const float d = 1.f / sqrtf(sum);
            sd[s] = d;
            if (blockIdx.x == 0) ws[DSOFF + s] = d;
        }
        __syncthreads();
    } else {
        if (tid < SS) sd[tid] = ws[DSOFF + tid];
        __syncthreads();
    }

    // ---- stage X (+ compute it if FIRST) ----
    if (q == 0 && act) {
        float4 xv;
        if (FIRST) {
            const float4* xr = (const float4*)(xin + (t*SS + s)*CIN);
            const float4 xa = xr[0], xb = xr[1];
            float a0 = bf[c0], a1 = bf[c0+1], a2 = bf[c0+2], a3 = bf[c0+3];
            const float xi[8] = {xa.x, xa.y, xa.z, xa.w, xb.x, xb.y, xb.z, xb.w};
            #pragma unroll
            for (int i = 0; i < CIN; ++i) {
                a0 += xi[i] * Wf[i*CW + c0];
                a1 += xi[i] * Wf[i*CW + c0+1];
                a2 += xi[i] * Wf[i*CW + c0+2];
                a3 += xi[i] * Wf[i*CW + c0+3];
            }
            xv = make_float4(a0, a1, a2, a3);
            *(float4*)(ws + XOFF + t*NSC + s*CW + c0) = xv;
        } else {
            xv = *(const float4*)(ws + XOFF + t*NSC + s*CW + c0);
        }
        sX[s] = xv;
        const float d = sd[s];
        sXd[s] = make_float4(xv.x*d, xv.y*d, xv.z*d, xv.w*d);
    }
    __syncthreads();

    // ---- U1 = 0.5 d_s sum_sp As[sp,s] * (d_sp X[sp,:]) ----
    if (act) {
        float4 acc = make_float4(0.f, 0.f, 0.f, 0.f);
        #pragma unroll 5
        for (int sp = q*50; sp < q*50 + 50; ++sp) {
            const float a = As[sp*SS + s];
            const float4 xd = sXd[sp];
            acc.x += a*xd.x; acc.y += a*xd.y; acc.z += a*xd.z; acc.w += a*xd.w;
        }
        spart[q][s] = acc;
    }
    __syncthreads();
    float4 u1 = make_float4(0.f, 0.f, 0.f, 0.f);
    if (q == 0 && act) {
        const float4 p0 = spart[0][s], p1 = spart[1][s];
        const float4 p2 = spart[2][s], p3 = spart[3][s];
        const float h = 0.5f * sd[s];
        u1 = make_float4((p0.x+p1.x+p2.x+p3.x)*h, (p0.y+p1.y+p2.y+p3.y)*h,
                         (p0.z+p1.z+p2.z+p3.z)*h, (p0.w+p1.w+p2.w+p3.w)*h);
        const float d = sd[s];
        sU[s] = make_float4(u1.x*d, u1.y*d, u1.z*d, u1.w*d);
    }
    __syncthreads();

    // ---- U2 = 0.5 d_s sum_sp As[sp,s] * (d_sp U1[sp,:]) ----
    if (act) {
        float4 acc = make_float4(0.f, 0.f, 0.f, 0.f);
        #pragma unroll 5
        for (int sp = q*50; sp < q*50 + 50; ++sp) {
            const float a = As[sp*SS + s];
            const float4 ud = sU[sp];
            acc.x += a*ud.x; acc.y += a*ud.y; acc.z += a*ud.z; acc.w += a*ud.w;
        }
        spart[q][s] = acc;
    }
    __syncthreads();
    if (q == 0 && act) {
        const float4 p0 = spart[0][s], p1 = spart[1][s];
        const float4 p2 = spart[2][s], p3 = spart[3][s];
        const float h = 0.5f * sd[s];
        const float4 u2 = make_float4((p0.x+p1.x+p2.x+p3.x)*h, (p0.y+p1.y+p2.y+p3.y)*h,
                                      (p0.z+p1.z+p2.z+p3.z)*h, (p0.w+p1.w+p2.w+p3.w)*h);
        const float s0 = svec[b*4+0], s1 = svec[b*4+1];
        const float s2 = svec[b*4+2], s3 = svec[b*4+3];
        const float b00 = s0*s0, b01 = 2.f*s0*s1, b02 = s1*s1;
        const float b10 = 2.f*s0*s2, b11 = 2.f*(s0*s3 + s1*s2), b12 = 2.f*s1*s3;
        const float b20 = s2*s2, b21 = 2.f*s2*s3, b22 = s3*s3;
        const float4 xv = sX[s];
        const int gid = t*NSC + s*CW + c0;
        *(float4*)(ws + M0AOFF + gid) = make_float4(
            s0*xv.x + s1*u1.x, s0*xv.y + s1*u1.y,
            s0*xv.z + s1*u1.z, s0*xv.w + s1*u1.w);
        *(float4*)(ws + M0BOFF + gid) = make_float4(
            b00*xv.x + b01*u1.x + b02*u2.x, b00*xv.y + b01*u1.y + b02*u2.y,
            b00*xv.z + b01*u1.z + b02*u2.z, b00*xv.w + b01*u1.w + b02*u2.w);
        *(float4*)(ws + M1OFF + gid) = make_float4(
            s2*xv.x + s3*u1.x, s2*xv.y + s3*u1.y,
            s2*xv.z + s3*u1.z, s2*xv.w + s3*u1.w);
        *(float4*)(ws + M2OFF + gid) = make_float4(
            b10*xv.x + b11*u1.x + b12*u2.x, b10*xv.y + b11*u1.y + b12*u2.y,
            b10*xv.z + b11*u1.z + b12*u2.z, b10*xv.w + b11*u1.w + b12*u2.w);
        *(float4*)(ws + M3OFF + gid) = make_float4(
            b20*xv.x + b21*u1.x + b22*u2.x, b20*xv.y + b21*u1.y + b22*u2.y,
            b20*xv.z + b21*u1.z + b22*u2.z, b20*xv.w + b21*u1.w + b22*u2.w);
    }
}

// ---------------- kB: temporal dots + epilogue (+ final out for last) -----
__global__ __launch_bounds__(256)
void kB(const float* __restrict__ xin, const float* __restrict__ H,
        const float* __restrict__ mW1, const float* __restrict__ mb1,
        const float* __restrict__ mW2, const float* __restrict__ mb2,
        const float* __restrict__ Wl, const float* __restrict__ bl,
        float* __restrict__ ws, float* __restrict__ out, int b, int last) {
    __shared__ float sAt[2*TT*TT];     // At-hat, At-hat^2
    __shared__ float sH[3*CW*CW];
    __shared__ float sW1[(CW+CIN)*CW];
    __shared__ float sW2[CW*CW];
    __shared__ float sb1[CW], sb2[CW];
    __shared__ float sx[256], sp1[256], sp2[256], sxt[256], sh[256];
    __shared__ float sxin[8*CIN];

    const int tid = threadIdx.x;
    const int gid = blockIdx.x*256 + tid;
    const int t = gid / NSC;           // block-uniform
    const int sc = gid - t*NSC;
    const int r = tid >> 5, c = tid & 31;
    const int node = gid >> 5;

    const float* Hb = H   + b*3*CW*CW;
    const float* W1 = mW1 + b*(CW+CIN)*CW;
    const float* W2 = mW2 + b*CW*CW;

    for (int i = tid; i < 2*TT*TT; i += 256) sAt[i] = ws[ATOFF + i];
    for (int i = tid; i < 3*CW*CW; i += 256) sH[i] = Hb[i];
    for (int i = tid; i < (CW+CIN)*CW; i += 256) sW1[i] = W1[i];
    for (int i = tid; i < CW*CW; i += 256) sW2[i] = W2[i];
    if (tid < CW) { sb1[tid] = mb1[b*CW + tid]; sb2[tid] = mb2[b*CW + tid]; }
    sx[tid] = ws[XOFF + gid];
    if (c < CIN) sxin[r*CIN + c] = xin[node*CIN + c];
    __syncthreads();

    {
        const float* M1 = ws + M1OFF + sc;
        const float* M2 = ws + M2OFF + sc;
        const float* M3 = ws + M3OFF + sc;
        float d1 = 0.f, d2 = 0.f, d3 = 0.f;
        #pragma unroll
        for (int tp = 0; tp < TT; ++tp) {
            const float a1 = sAt[t*TT + tp];
            const float a2 = sAt[TT*TT + t*TT + tp];
            d1 += a1 * M1[tp*NSC];
            d2 += a1 * M2[tp*NSC];
            d3 += a2 * M3[tp*NSC];
        }
        sp1[tid] = ws[M0AOFF + gid] + d1;
        sp2[tid] = ws[M0BOFF + gid] + d2 + d3;
    }
    __syncthreads();
    {
        float acc = 0.f;
        #pragma unroll 8
        for (int cp = 0; cp < CW; ++cp) {
            acc += sx[r*CW + cp]  * sH[cp*CW + c];
            acc += sp1[r*CW + cp] * sH[CW*CW + cp*CW + c];
            acc += sp2[r*CW + cp] * sH[2*CW*CW + cp*CW + c];
        }
        sxt[tid] = tanhf(acc);
    }
    __syncthreads();
    {
        float h = sb1[c];
        #pragma unroll 8
        for (int cp = 0; cp < CW; ++cp) h += sxt[r*CW + cp] * sW1[cp*CW + c];
        #pragma unroll
        for (int i = 0; i < CIN; ++i) h += sxin[r*CIN + i] * sW1[(CW+i)*CW + c];
        sh[tid] = fmaxf(h, 0.f);
    }
    __syncthreads();
    {
        float xn = sb2[c];
        #pragma unroll 8
        for (int cp = 0; cp < CW; ++cp) xn += sh[r*CW + cp] * sW2[cp*CW + c];
        if (!last) {
            ws[XOFF + gid] = xn;
        } else {
            float v = xn * Wl[c];
            #pragma unroll
            for (int off = 16; off; off >>= 1) v += __shfl_xor(v, off, 64);
            if (c == 0) out[node] = v + bl[0];
        }
    }
}

extern "C" void kernel_launch(void* const* d_in, const int* in_sizes, int n_in,
                              void* d_out, int out_size, void* d_ws, size_t ws_size,
                              hipStream_t stream) {
    const float* xin   = (const float*)d_in[0];
    const float* Adj_t = (const float*)d_in[1];
    const float* Adj_s = (const float*)d_in[2];
    const float* H     = (const float*)d_in[3];
    const float* svec  = (const float*)d_in[4];
    const float* Wf    = (const float*)d_in[5];
    const float* bf    = (const float*)d_in[6];
    const float* Wl    = (const float*)d_in[7];
    const float* bl    = (const float*)d_in[8];
    const float* mW1   = (const float*)d_in[9];
    const float* mb1   = (const float*)d_in[10];
    const float* mW2   = (const float*)d_in[11];
    const float* mb2   = (const float*)d_in[12];
    float* out = (float*)d_out;
    float* ws  = (float*)d_ws;

    kSp<true><<<193, 1024, 0, stream>>>(xin, Adj_t, Adj_s, Wf, bf, svec, ws, 0);
    kB<<<600, 256, 0, stream>>>(xin, H, mW1, mb1, mW2, mb2, Wl, bl,
                                ws, out, 0, 0);
    kSp<false><<<192, 1024, 0, stream>>>(xin, Adj_t, Adj_s, Wf, bf, svec, ws, 1);
    kB<<<600, 256, 0, stream>>>(xin, H, mW1, mb1, mW2, mb2, Wl, bl,
                                ws, out, 1, 1);
}